// Round 13
// baseline (2521.827 us; speedup 1.0000x reference)
//
#include <hip/hip_runtime.h>
#include <hip/hip_bf16.h>
#include <stdint.h>
#include <stddef.h>

#define TPAD 320   // padded time stride (300 real + 20 pad)
#define TREAL 300

// Python-f64 pool weight: float(1.1*10.0)  (validated exact, rounds 7-13)
#define POOL_W   11.000000000000002

typedef double v4d __attribute__((ext_vector_type(4)));

static __device__ __forceinline__ float bf2f(uint16_t b) {
    return __uint_as_float(((uint32_t)b) << 16);
}

// ---------------------------------------------------------------------------
// f64 truncated-alpha IIR + refractory scan (validated exact, rounds 8-13).
// ---------------------------------------------------------------------------
struct IIRC { double DD, C1, C2, C3, DR; };
static __device__ __forceinline__ IIRC iirc_make() {
    IIRC c;
    c.DD = exp(-0.1);
    c.C1 = exp(1.0) / 10.0;
    c.C2 = exp(-9.0) / 10.0;
    c.C3 = 10.0 * exp(-9.0);
    c.DR = exp(-1.0);
    return c;
}
struct IIRS { double P, Q, P2, Q2, r; };
static __device__ __forceinline__ void iirs_init(IIRS& s) {
    s.P = 0.0; s.Q = 0.0; s.P2 = 0.0; s.Q2 = 0.0; s.r = 0.0;
}
static __device__ __forceinline__ bool iir_step(const IIRC& c, IIRS& st,
                                                double x, double xd) {
    double Qn  = c.DD * (st.Q + st.P);
    double Pn  = fma(c.DD, st.P, x);
    double Q2n = c.DD * (st.Q2 + st.P2);
    double P2n = fma(c.DD, st.P2, xd);
    double a = c.C1 * Qn - c.C2 * Q2n - c.C3 * P2n;
    double u = a + st.r;
    bool s = (u >= 10.0);
    st.r = c.DR * (st.r - (s ? 20.0 : 0.0));
    st.P = Pn; st.Q = Qn; st.P2 = P2n; st.Q2 = Q2n;
    return s;
}

// ---------------------------------------------------------------------------
__global__ void detect_kernel(const uint16_t* __restrict__ w1raw, int* __restrict__ flag)
{
    if (threadIdx.x == 0 && blockIdx.x == 0) {
        int sane = 1;
        for (int i = 0; i < 800; ++i) {
            int e = (w1raw[i] >> 7) & 0xFF;
            if (e >= 131) { sane = 0; break; }
        }
        *flag = sane;   // 1 = bf16, 0 = f32
    }
}

// ---------------------------------------------------------------------------
// MFMA f64 LAYOUT-DISCOVERY probe (r12, VALIDATED: matched on HW and the
// full run passed absmax 0.0 -> exact-sum theory + discovered layout are
// both correct). 6 hypotheses: {B packing: lane=16k+j | lane=4j+k} x
// {D map: i=4*(l>>4)+r | i=(l>>4)+4*r | transposed}. A fixed: i=lane&15,
// k=lane>>4 (confirmed by r12 pass). mode = 1+combo, 0 = serial fallback.
// ---------------------------------------------------------------------------
static __device__ __forceinline__ double probe_w(int a, int b, int s) {
    uint32_t h = (uint32_t)(a * 73856093) ^ (uint32_t)(b * 19349663)
               ^ (uint32_t)(s * 83492791) ^ 0x9e3779b9u;
    h ^= h >> 13; h *= 0x85ebca6bu; h ^= h >> 16;
    int m = 128 + (int)(h & 127u);          // 8-bit mantissa
    int e = -12 + (int)((h >> 7) & 7u);     // small exponent spread
    double v = ldexp((double)m, e);
    return ((h >> 15) & 1u) ? -v : v;
}
static __device__ __forceinline__ double probe_x(int i, int k, int s) {
    return (double)(((i * 5 + k * 3 + s) % 7) < 3 ? 1 : 0);
}
static __device__ __forceinline__ void d_decode(int dvar, int lane, int r,
                                                int& i, int& j) {
    int l15 = lane & 15, l4 = lane >> 4;
    if (dvar == 0)      { i = 4 * l4 + r;  j = l15; }
    else if (dvar == 1) { i = l4 + 4 * r;  j = l15; }
    else                { i = l15;         j = 4 * l4 + r; }
}

__global__ void mfma_probe_kernel(int* __restrict__ mode)
{
    const int lane = (int)threadIdx.x & 63;
    const int l15 = lane & 15;
    const int l4  = lane >> 4;
    int found = 0;
    for (int c = 0; c < 6; ++c) {
        int bvar = c / 3, dvar = c % 3;
        bool ok = true;
        for (int s = 0; s < 4; ++s) {
            double av = probe_x(l15, l4, s);                       // A[i][k]
            double bv = (bvar == 0) ? probe_w(l4, l15, s)          // B: 16k+j
                                    : probe_w(lane & 3, lane >> 2, s); // 4j+k
            v4d cc;
            #pragma unroll
            for (int r = 0; r < 4; ++r) {
                int i, j; d_decode(dvar, lane, r, i, j);
                cc[r] = probe_w(32 + i, j, s + 17);
            }
            v4d d = __builtin_amdgcn_mfma_f64_16x16x4f64(av, bv, cc, 0, 0, 0);
            #pragma unroll
            for (int r = 0; r < 4; ++r) {
                int i, j; d_decode(dvar, lane, r, i, j);
                double e = probe_w(32 + i, j, s + 17);
                #pragma unroll
                for (int k = 0; k < 4; ++k)
                    e = fma(probe_x(i, k, s), probe_w(k, j, s), e);  // exact
                ok &= (__double_as_longlong(e) == __double_as_longlong(d[r]));
            }
        }
        unsigned long long bo = __ballot(ok);
        if (bo == ~0ull && found == 0) found = c + 1;
    }
    if (threadIdx.x == 0) *mode = found;
}

// Conv weights -> f64, transposed to [co_group][tap][16 co-in-group] (serial).
__global__ __launch_bounds__(256) void wtrans_kernel(
    const void* __restrict__ w, double* __restrict__ out, int Co, int CKK,
    const int* __restrict__ flag)
{
    int i = blockIdx.x * 256 + threadIdx.x;
    if (i >= Co * CKK) return;
    int co = i / CKK, r = i - co * CKK;
    double v = (*flag) ? (double)bf2f(((const uint16_t*)w)[i])
                       : (double)((const float*)w)[i];
    out[(size_t)(co >> 4) * CKK * 16 + (size_t)r * 16 + (co & 15)] = v;
}

// Conv weights -> f64 MFMA B-fragments [gy][gks][lane]; lane packing per
// probed B-variant. tap = gks*4 + k; taps >= CKK zero-padded (L1 ragged).
__global__ __launch_bounds__(256) void wtrans_frag_kernel(
    const void* __restrict__ w, double* __restrict__ out,
    int CKK, int KS_TOTAL, int total,
    const int* __restrict__ flag, const int* __restrict__ mode)
{
    int i = blockIdx.x * 256 + threadIdx.x;
    if (i >= total) return;
    int md = *mode;
    int bvar = (md > 0) ? (md - 1) / 3 : 0;
    int lane = i & 63;
    int gks  = (i >> 6) % KS_TOTAL;
    int gy   = (i >> 6) / KS_TOTAL;
    int kl, col;
    if (bvar == 0) { kl = lane >> 4; col = lane & 15; }
    else           { kl = lane & 3;  col = lane >> 2; }
    int tap  = gks * 4 + kl;
    int co   = gy * 16 + col;
    double v = 0.0;
    if (tap < CKK) {
        int src = co * CKK + tap;
        v = (*flag) ? (double)bf2f(((const uint16_t*)w)[src])
                    : (double)((const float*)w)[src];
    }
    out[i] = v;
}

// Dense weights -> f32 (bf16->f32 exact)
__global__ __launch_bounds__(256) void wcvt_kernel(
    const void* __restrict__ w, float* __restrict__ out, int n, const int* __restrict__ flag)
{
    int i = blockIdx.x * 256 + threadIdx.x;
    if (i >= n) return;
    out[i] = (*flag) ? bf2f(((const uint16_t*)w)[i]) : ((const float*)w)[i];
}

__global__ __launch_bounds__(320) void convert_kernel(
    const void* __restrict__ s_in, uint8_t* __restrict__ u8, const int* __restrict__ flag)
{
    int row = blockIdx.x;
    int t = threadIdx.x;
    uint8_t v = 0;
    if (t < TREAL) {
        float x = (*flag) ? bf2f(((const uint16_t*)s_in)[(size_t)row * TREAL + t])
                          : ((const float*)s_in)[(size_t)row * TREAL + t];
        v = (x >= 0.5f) ? 1 : 0;
    }
    u8[(size_t)row * TPAD + t] = v;
}

// ---------------------------------------------------------------------------
// Conv -> z (f64) SERIAL: r9 body verbatim (155 us L3/L5), early-exits when
// MFMA mode active. Separate kernel so MFMA path can't inflate regalloc.
// ---------------------------------------------------------------------------
template<int Ci, int CIB, int K, int Hi>
__global__ __launch_bounds__(320, 3) void conv_z_kernel(
    const uint8_t* __restrict__ sprev,
    const double* __restrict__ Wt,
    double* __restrict__ z,
    int Co_total, const int* __restrict__ mode)
{
    if (*mode != 0) return;
    constexpr int P = 1;
    constexpr int Wi = Hi;
    constexpr int Ho = Hi + 2 * P - K + 1;
    constexpr int Wo = Ho;
    constexpr int KK = K * K;
    constexpr int CKK = Ci * KK;
    constexpr int CW = K + 1;
    constexpr int NROW = CIB * K * CW;
    constexpr int NPASS = Ci / CIB;
    constexpr int WTILE = CIB * KK * 16;
    static_assert(Ci % CIB == 0, "pass split");
    static_assert(Wo % 2 == 0, "pair split");
    static_assert(NROW * 320 + WTILE * 8 <= 60 * 1024, "LDS over limit");

    __shared__ uint32_t stage[NROW * 80];
    __shared__ double wtile[WTILE];

    const int t   = threadIdx.x;
    const int h   = (int)blockIdx.x / (Wo / 2);
    const int w   = ((int)blockIdx.x % (Wo / 2)) * 2;
    const int gy  = (int)blockIdx.y;
    const int co0 = gy * 16;
    const int b   = (int)blockIdx.z;

    double acc0[16], acc1[16];
    #pragma unroll
    for (int c = 0; c < 16; ++c) { acc0[c] = 0.0; acc1[c] = 0.0; }

    const size_t in_b = (size_t)b * Ci * Hi * Wi * TPAD;
    const double* wg = Wt + (size_t)gy * CKK * 16;

    for (int p = 0; p < NPASS; ++p) {
        const int ci0 = p * CIB;
        __syncthreads();
        for (int idx = t; idx < NROW * 20; idx += 320) {
            int r  = idx / 20, dw = idx - (idx / 20) * 20;
            int cl = r / (K * CW);
            int rem = r - cl * (K * CW);
            int ky = rem / CW, cx = rem - ky * CW;
            int row = h - P + ky;
            int col = w - P + cx;
            uint4 v = make_uint4(0, 0, 0, 0);
            if ((unsigned)row < (unsigned)Hi && (unsigned)col < (unsigned)Wi)
                v = *(const uint4*)(sprev + in_b +
                      (((size_t)(ci0 + cl) * Hi + row) * Wi + col) * TPAD + dw * 16);
            ((uint4*)stage)[(size_t)r * 20 + dw] = v;
        }
        for (int i = t; i < WTILE; i += 320)
            wtile[i] = wg[(size_t)ci0 * KK * 16 + i];
        __syncthreads();

        const uint8_t* sbytes = (const uint8_t*)stage;
        #pragma unroll 2
        for (int cl = 0; cl < CIB; ++cl) {
            #pragma unroll
            for (int ky = 0; ky < K; ++ky) {
                #pragma unroll
                for (int kx = 0; kx < K; ++kx) {
                    const int rbase = ((cl * K + ky) * CW + kx) * 320;
                    double x0 = (double)sbytes[rbase + t];
                    double x1 = (double)sbytes[rbase + 320 + t];
                    const double* wrow = wtile + (cl * KK + ky * K + kx) * 16;
                    #pragma unroll
                    for (int c = 0; c < 16; ++c) {
                        double wv = wrow[c];
                        acc0[c] = fma(wv, x0, acc0[c]);
                        acc1[c] = fma(wv, x1, acc1[c]);
                    }
                }
            }
        }
    }

    #pragma unroll
    for (int c = 0; c < 16; ++c) {
        size_t row0 = (((size_t)b * Co_total + co0 + c) * Ho + h) * Wo + w;
        z[row0 * TPAD + t]          = acc0[c];
        z[(row0 + 1) * TPAD + t]    = acc1[c];
    }
}

// ---------------------------------------------------------------------------
// Conv -> z (f64) MFMA, DIRECT-GLOBAL FEED (round 13). r12 proved the MFMA
// path numerically (absmax 0.0, MfmaUtil 38%) but it was feed-bound: LDS
// byte reads of A were 4-way bank-conflicted (1.97M conflicts), occupancy
// 18%. Fix: drop LDS/staging/barriers entirely. Per kstep: bv = coalesced
// 512B/wave global load (L2-hot); av = 8 clamped global byte loads (16
// consecutive bytes per l4 group -> coalesced); invalid lanes -> 0.0 via
// select (padded k-slots have B=0, so garbage x 0 = 0, exact). Values and
// store identical to r12 -> absmax 0.0 preserved.
// Grid: (Ho*Wo/2, Co_total/16, Bg), block 320 (5 waves x 8 jb).
// ---------------------------------------------------------------------------
template<int Ci, int K, int Hi>
__global__ __launch_bounds__(320, 3) void conv_z_mfma_kernel(
    const uint8_t* __restrict__ sprev,
    const double* __restrict__ Wfrag,    // [Co/16][KS_TOTAL][64]
    double* __restrict__ z,
    int Co_total, const int* __restrict__ mode)
{
    const int md = *mode;
    if (md == 0) return;
    const int dvar = (md - 1) % 3;
    constexpr int P = 1;
    constexpr int Wi = Hi;
    constexpr int Ho = Hi + 2 * P - K + 1;
    constexpr int Wo = Ho;
    constexpr int KK = K * K;
    constexpr int CKK = Ci * KK;
    constexpr int KS_TOTAL = (CKK + 3) / 4;
    static_assert(Wo % 2 == 0, "pair split");

    const int t    = threadIdx.x;
    const int wave = t >> 6;
    const int lane = t & 63;
    const int l15  = lane & 15;
    const int l4   = lane >> 4;
    const int h    = (int)blockIdx.x / (Wo / 2);
    const int w    = ((int)blockIdx.x % (Wo / 2)) * 2;
    const int gy   = (int)blockIdx.y;
    const int co0  = gy * 16;
    const int b    = (int)blockIdx.z;

    v4d acc[8];
    #pragma unroll
    for (int jj = 0; jj < 8; ++jj) acc[jj] = (v4d)(0.0);

    const uint8_t* sp_b = sprev + (size_t)b * Ci * Hi * Wi * TPAD;
    const double* wf = Wfrag + (size_t)gy * KS_TOTAL * 64 + lane;

    for (int gks = 0; gks < KS_TOTAL; ++gks) {
        double bv = wf[(size_t)gks * 64];
        int ltap = gks * 4 + l4;
        int ci  = ltap / KK;
        int rem = ltap - ci * KK;
        int ky  = rem / K;
        int kx  = rem - ky * K;
        int row = h - P + ky;
        int col = w - P + kx;
        bool tv = (CKK % 4 == 0) || (ltap < CKK);
        bool vr = tv && ((unsigned)row < (unsigned)Hi);
        bool v0 = vr && ((unsigned)col < (unsigned)Wi);
        bool v1 = vr && ((unsigned)(col + 1) < (unsigned)Wi);
        int cic  = tv ? ci : 0;
        int rowc = vr ? row : 0;
        int c0   = v0 ? col : 0;
        int c1   = v1 ? (col + 1) : 0;
        const uint8_t* p0 = sp_b + (((size_t)cic * Hi + rowc) * Wi + c0) * TPAD + l15;
        const uint8_t* p1 = sp_b + (((size_t)cic * Hi + rowc) * Wi + c1) * TPAD + l15;
        #pragma unroll
        for (int q = 0; q < 4; ++q) {
            int tile = wave * 4 + q;
            double a0 = v0 ? (double)p0[tile * 16] : 0.0;
            acc[2 * q] = __builtin_amdgcn_mfma_f64_16x16x4f64(a0, bv, acc[2 * q], 0, 0, 0);
            double a1 = v1 ? (double)p1[tile * 16] : 0.0;
            acc[2 * q + 1] = __builtin_amdgcn_mfma_f64_16x16x4f64(a1, bv, acc[2 * q + 1], 0, 0, 0);
        }
    }

    // store per probed D-variant (wave-uniform branch), LINEAR z (r12-exact)
    if (dvar == 0) {
        #pragma unroll
        for (int jj = 0; jj < 8; ++jj) {
            int jb = wave * 8 + jj;
            int tile = jb >> 1, px = jb & 1;
            size_t row = (((size_t)b * Co_total + co0 + l15) * Ho + h) * Wo + w + px;
            *(v4d*)(z + row * TPAD + tile * 16 + l4 * 4) = acc[jj];
        }
    } else if (dvar == 1) {
        #pragma unroll
        for (int jj = 0; jj < 8; ++jj) {
            int jb = wave * 8 + jj;
            int tile = jb >> 1, px = jb & 1;
            size_t row = (((size_t)b * Co_total + co0 + l15) * Ho + h) * Wo + w + px;
            #pragma unroll
            for (int r = 0; r < 4; ++r)
                z[row * TPAD + tile * 16 + l4 + 4 * r] = acc[jj][r];
        }
    } else {
        #pragma unroll
        for (int jj = 0; jj < 8; ++jj) {
            int jb = wave * 8 + jj;
            int tile = jb >> 1, px = jb & 1;
            #pragma unroll
            for (int r = 0; r < 4; ++r) {
                size_t row = (((size_t)b * Co_total + co0 + 4 * l4 + r) * Ho + h) * Wo + w + px;
                z[row * TPAD + tile * 16 + l15] = acc[jj][r];
            }
        }
    }
}

// ---------------------------------------------------------------------------
// PSP + scan over z: 64 rows/block (r9, validated).
// ---------------------------------------------------------------------------
__global__ __launch_bounds__(256) void psp_scan_kernel(
    const double* __restrict__ z, uint8_t* __restrict__ sout, int N)
{
    __shared__ uint32_t bits[64 * 11];
    const int tid = threadIdx.x;
    const int n0 = blockIdx.x * 64;
    const int n = n0 + tid;
    const bool active = (tid < 64) && (n < N);

    if (active) {
        const double* zr = z + (size_t)n * TPAD;
        const IIRC c = iirc_make();
        IIRS st; iirs_init(st);
        uint32_t bw = 0;
        #pragma unroll 5
        for (int t0 = 0; t0 < 100; t0 += 4) {
            double2 xa = *(const double2*)(zr + t0);
            double2 xb = *(const double2*)(zr + t0 + 2);
            if (iir_step(c, st, xa.x, 0.0)) bw |= 1u << (t0 & 31);
            if (iir_step(c, st, xa.y, 0.0)) bw |= 1u << ((t0 + 1) & 31);
            if (iir_step(c, st, xb.x, 0.0)) bw |= 1u << ((t0 + 2) & 31);
            if (iir_step(c, st, xb.y, 0.0)) bw |= 1u << ((t0 + 3) & 31);
            if ((t0 & 31) == 28) { bits[tid * 11 + (t0 >> 5)] = bw; bw = 0; }
        }
        #pragma unroll 5
        for (int t0 = 100; t0 < TREAL; t0 += 4) {
            double2 xa = *(const double2*)(zr + t0);
            double2 xb = *(const double2*)(zr + t0 + 2);
            double2 da = *(const double2*)(zr + t0 - 100);
            double2 db = *(const double2*)(zr + t0 - 98);
            if (iir_step(c, st, xa.x, da.x)) bw |= 1u << (t0 & 31);
            if (iir_step(c, st, xa.y, da.y)) bw |= 1u << ((t0 + 1) & 31);
            if (iir_step(c, st, xb.x, db.x)) bw |= 1u << ((t0 + 2) & 31);
            if (iir_step(c, st, xb.y, db.y)) bw |= 1u << ((t0 + 3) & 31);
            if ((t0 & 31) == 28) { bits[tid * 11 + (t0 >> 5)] = bw; bw = 0; }
        }
        bits[tid * 11 + 9] = bw;
    }
    __syncthreads();

    for (int task = tid; task < 64 * 80; task += 256) {
        int nl = task / 80, w = task - nl * 80;
        int ng = n0 + nl;
        if (ng >= N) continue;
        int tb = w * 4;
        uint32_t word = bits[nl * 11 + (tb >> 5)];
        uint32_t o = 0;
        #pragma unroll
        for (int j = 0; j < 4; ++j)
            if ((word >> ((tb + j) & 31)) & 1u) o |= 1u << (8 * j);
        *(uint32_t*)(sout + (size_t)ng * TPAD + tb) = o;
    }
}

// ---------------------------------------------------------------------------
// Pool + PSP + scan v2 (validated r13): LDS cnt tile, coalesced in/out.
// ---------------------------------------------------------------------------
template<int C, int Hi>
__global__ __launch_bounds__(256) void pool_psp_v2_kernel(
    const uint8_t* __restrict__ sprev, uint8_t* __restrict__ sout, int N)
{
    constexpr int Wi = Hi, Ho = Hi / 2, Wo = Wi / 2;
    __shared__ uint32_t cnt[128 * 81];
    __shared__ uint32_t bits[128 * 11];
    const int tid = threadIdx.x;
    const int n0 = blockIdx.x * 128;

    for (int task = tid; task < 128 * 80; task += 256) {
        int nl = task / 80, w = task - nl * 80;
        int n = n0 + nl;
        if (n >= N) continue;
        int wo = n % Wo;  int r1 = n / Wo;
        int ho = r1 % Ho; int r2 = r1 / Ho;
        int cc = r2 % C;  int b  = r2 / C;
        const uint8_t* p0 = sprev +
            ((((size_t)b * C + cc) * Hi + 2 * ho) * Wi + 2 * wo) * TPAD + w * 4;
        uint32_t a0 = *(const uint32_t*)p0;
        uint32_t a1 = *(const uint32_t*)(p0 + TPAD);
        uint32_t a2 = *(const uint32_t*)(p0 + (size_t)Wi * TPAD);
        uint32_t a3 = *(const uint32_t*)(p0 + (size_t)(Wi + 1) * TPAD);
        cnt[nl * 81 + w] = a0 + a1 + a2 + a3;
    }
    __syncthreads();

    if (tid < 128 && n0 + tid < N) {
        const uint8_t* cb = (const uint8_t*)cnt + (size_t)tid * 324;
        const IIRC c = iirc_make();
        IIRS st; iirs_init(st);
        uint32_t bw = 0;
        for (int t = 0; t < 100; ++t) {
            double x = POOL_W * (double)cb[t];
            if (iir_step(c, st, x, 0.0)) bw |= 1u << (t & 31);
            if ((t & 31) == 31) { bits[tid * 11 + (t >> 5)] = bw; bw = 0; }
        }
        for (int t = 100; t < TREAL; ++t) {
            double x  = POOL_W * (double)cb[t];
            double xd = POOL_W * (double)cb[t - 100];
            if (iir_step(c, st, x, xd)) bw |= 1u << (t & 31);
            if ((t & 31) == 31) { bits[tid * 11 + (t >> 5)] = bw; bw = 0; }
        }
        bits[tid * 11 + 9] = bw;
    }
    __syncthreads();

    for (int task = tid; task < 128 * 80; task += 256) {
        int nl = task / 80, w = task - nl * 80;
        int n = n0 + nl;
        if (n >= N) continue;
        int tb = w * 4;
        uint32_t word = bits[nl * 11 + (tb >> 5)];
        uint32_t o = 0;
        #pragma unroll
        for (int j = 0; j < 4; ++j)
            if ((word >> ((tb + j) & 31)) & 1u) o |= 1u << (8 * j);
        *(uint32_t*)(sout + (size_t)n * TPAD + tb) = o;
    }
}

// ---------------------------------------------------------------------------
// Dense partials: grid (5, B, 16) (validated r9+).
// ---------------------------------------------------------------------------
__global__ __launch_bounds__(256) void dense_partial_kernel(
    const uint8_t* __restrict__ s5, const float* __restrict__ Wf,
    double* __restrict__ partial)
{
    const int tc = blockIdx.x, b = blockIdx.y, p = blockIdx.z;
    const int tid = threadIdx.x;
    const int tl = tid & 63, slot = tid >> 6;
    const int t = tc * 64 + tl;
    const int i0 = p * 256 + slot * 64;
    double acc[10];
    #pragma unroll
    for (int o = 0; o < 10; ++o) acc[o] = 0.0;
    const uint8_t* sp = s5 + ((size_t)b * 4096 + i0) * TPAD + t;
    for (int i = 0; i < 64; ++i) {
        float f = (float)sp[(size_t)i * TPAD];
        if (__any(f != 0.f)) {
            #pragma unroll
            for (int o = 0; o < 10; ++o)
                acc[o] = fma((double)Wf[o * 4096 + i0 + i], (double)f, acc[o]);
        }
    }
    __shared__ double red[4][64][10];
    #pragma unroll
    for (int o = 0; o < 10; ++o) red[slot][tl][o] = acc[o];
    __syncthreads();
    if (slot == 0) {
        #pragma unroll
        for (int o = 0; o < 10; ++o) {
            double v = ((red[0][tl][o] + red[1][tl][o]) + red[2][tl][o]) + red[3][tl][o];
            partial[((size_t)p * 160 + (size_t)b * 10 + o) * TPAD + t] = v;
        }
    }
}

// ---------------------------------------------------------------------------
// Final: one launch, block per (b,o) row (validated rounds 9-13).
// ---------------------------------------------------------------------------
__global__ __launch_bounds__(320) void psp_out_final_kernel(
    const double* __restrict__ partial, void* __restrict__ out,
    const int* __restrict__ flag)
{
    __shared__ double xs[TPAD];
    __shared__ uint8_t sb[TREAL];
    const int n = blockIdx.x;
    const int t = threadIdx.x;
    double v = 0.0;
    #pragma unroll
    for (int p = 0; p < 16; ++p)
        v += partial[((size_t)p * 160 + n) * TPAD + t];
    xs[t] = v;
    __syncthreads();
    if (t == 0) {
        const IIRC c = iirc_make();
        IIRS st; iirs_init(st);
        for (int i = 0; i < TREAL; ++i) {
            double xd = (i >= 100) ? xs[i - 100] : 0.0;
            sb[i] = iir_step(c, st, xs[i], xd) ? 1 : 0;
        }
    }
    __syncthreads();
    if (t < TREAL) {
        size_t e = (size_t)n * TREAL + t;
        if (*flag) ((uint16_t*)out)[e] = sb[t] ? 0x3F80 : 0;
        else       ((float*)out)[e]    = sb[t] ? 1.0f : 0.0f;
    }
}

// ---------------------------------------------------------------------------
__global__ __launch_bounds__(256) void fill_kernel(float* __restrict__ out, int n, float v)
{
    int i = blockIdx.x * 256 + threadIdx.x;
    if (i < n) out[i] = v;
}

// ---------------------------------------------------------------------------
static inline size_t alignup(size_t x) { return (x + 255) & ~(size_t)255; }
static inline int pick_bg(size_t per_b, size_t budget) {
    const int cand[5] = {16, 8, 4, 2, 1};
    for (int k = 0; k < 5; ++k)
        if (per_b * (size_t)cand[k] <= budget) return cand[k];
    return 0;
}

extern "C" void kernel_launch(void* const* d_in, const int* in_sizes, int n_in,
                              void* d_out, int out_size, void* d_ws, size_t ws_size,
                              hipStream_t stream)
{
    if (n_in != 5 || in_sizes[0] != 16 * 2 * 34 * 34 * 300 || in_sizes[1] != 800 ||
        in_sizes[2] != 4608 || in_sizes[3] != 18432 || in_sizes[4] != 40960 ||
        out_size != 16 * 10 * 300) {
        fill_kernel<<<(out_size + 255) / 256, 256, 0, stream>>>((float*)d_out, out_size, 2.0e5f);
        return;
    }

    const size_t flag_sz  = alignup(sizeof(int));
    const size_t mode_sz  = alignup(sizeof(int));
    const size_t w64_sz   = alignup((size_t)(800 + 4608 + 18432) * 8);
    const size_t wfrag_sz = alignup((size_t)(832 + 4608 + 18432) * 8);
    const size_t wf32_sz  = alignup((size_t)40960 * 4);
    const size_t sin8_sz  = alignup((size_t)16 * 2 * 34 * 34 * TPAD);
    const size_t dpart_sz = alignup((size_t)16 * 160 * TPAD * 8);
    const size_t sA_sz    = alignup((size_t)16 * 16384 * TPAD);
    const size_t sB_sz    = alignup((size_t)16 * 4096 * TPAD);
    const size_t base_sz  = flag_sz + mode_sz + w64_sz + wfrag_sz + wf32_sz +
                            sin8_sz + dpart_sz + sA_sz + sB_sz;
    if (base_sz + 256 > ws_size) {
        fill_kernel<<<(out_size + 255) / 256, 256, 0, stream>>>((float*)d_out, out_size, 1.0e5f);
        return;
    }
    const size_t zbud = ws_size - base_sz - 256;

    const size_t zb1 = (size_t)16 * 1024 * TPAD * 8;
    const size_t zb3 = (size_t)32 * 256 * TPAD * 8;
    const size_t zb5 = (size_t)64 * 64 * TPAD * 8;
    const int bg1 = pick_bg(zb1, zbud), bg3 = pick_bg(zb3, zbud), bg5 = pick_bg(zb5, zbud);
    if (bg1 == 0 || bg3 == 0 || bg5 == 0) {
        fill_kernel<<<(out_size + 255) / 256, 256, 0, stream>>>((float*)d_out, out_size, 1.0e5f);
        return;
    }

    char* base = (char*)d_ws;
    int* flag = (int*)base;          base += flag_sz;
    int* mode = (int*)base;          base += mode_sz;
    double* w64 = (double*)base;     base += w64_sz;
    double* wfrag = (double*)base;   base += wfrag_sz;
    float* wf32 = (float*)base;      base += wf32_sz;
    uint8_t* sin8 = (uint8_t*)base;  base += sin8_sz;
    double* dpart = (double*)base;   base += dpart_sz;
    uint8_t* sA = (uint8_t*)base;    base += sA_sz;
    uint8_t* sB = (uint8_t*)base;    base += sB_sz;
    double* z64 = (double*)base;

    detect_kernel<<<1, 64, 0, stream>>>((const uint16_t*)d_in[1], flag);
    mfma_probe_kernel<<<1, 64, 0, stream>>>(mode);

    double* Wt1 = w64;                 // [1][50][16]
    double* Wt2 = w64 + 800;           // [2][144][16]
    double* Wt3 = w64 + 800 + 4608;    // [4][288][16]
    wtrans_kernel<<<(800 + 255) / 256, 256, 0, stream>>>(d_in[1], Wt1, 16, 50, flag);
    wtrans_kernel<<<(4608 + 255) / 256, 256, 0, stream>>>(d_in[2], Wt2, 32, 144, flag);
    wtrans_kernel<<<(18432 + 255) / 256, 256, 0, stream>>>(d_in[3], Wt3, 64, 288, flag);

    double* Wf1 = wfrag;                  // [1][13][64]
    double* Wf2 = wfrag + 832;            // [2][36][64]
    double* Wf3 = wfrag + 832 + 4608;     // [4][72][64]
    wtrans_frag_kernel<<<(832 + 255) / 256, 256, 0, stream>>>(
        d_in[1], Wf1, 50, 13, 832, flag, mode);
    wtrans_frag_kernel<<<(4608 + 255) / 256, 256, 0, stream>>>(
        d_in[2], Wf2, 144, 36, 4608, flag, mode);
    wtrans_frag_kernel<<<(18432 + 255) / 256, 256, 0, stream>>>(
        d_in[3], Wf3, 288, 72, 18432, flag, mode);

    wcvt_kernel<<<(40960 + 255) / 256, 256, 0, stream>>>(d_in[4], wf32, 40960, flag);
    convert_kernel<<<16 * 2 * 34 * 34, 320, 0, stream>>>(d_in[0], sin8, flag);

    // L1: conv 2->16, 5x5 pad1, 34->32
    for (int b0 = 0; b0 < 16; b0 += bg1) {
        conv_z_kernel<2, 2, 5, 34><<<dim3(32 * 16, 1, bg1), 320, 0, stream>>>(
            sin8 + (size_t)b0 * 2 * 34 * 34 * TPAD, Wt1, z64, 16, mode);
        conv_z_mfma_kernel<2, 5, 34><<<dim3(32 * 16, 1, bg1), 320, 0, stream>>>(
            sin8 + (size_t)b0 * 2 * 34 * 34 * TPAD, Wf1, z64, 16, mode);
        int N = bg1 * 16384;
        psp_scan_kernel<<<(N + 63) / 64, 256, 0, stream>>>(
            z64, sA + (size_t)b0 * 16384 * TPAD, N);
    }
    // L2: pool 32->16
    pool_psp_v2_kernel<16, 32><<<(16 * 4096 + 127) / 128, 256, 0, stream>>>(
        sA, sB, 16 * 4096);
    // L3: conv 16->32, 3x3 pad1, 16->16
    for (int b0 = 0; b0 < 16; b0 += bg3) {
        conv_z_kernel<16, 8, 3, 16><<<dim3(16 * 8, 2, bg3), 320, 0, stream>>>(
            sB + (size_t)b0 * 16 * 256 * TPAD, Wt2, z64, 32, mode);
        conv_z_mfma_kernel<16, 3, 16><<<dim3(16 * 8, 2, bg3), 320, 0, stream>>>(
            sB + (size_t)b0 * 16 * 256 * TPAD, Wf2, z64, 32, mode);
        int N = bg3 * 8192;
        psp_scan_kernel<<<(N + 63) / 64, 256, 0, stream>>>(
            z64, sA + (size_t)b0 * 8192 * TPAD, N);
    }
    // L4: pool 16->8
    pool_psp_v2_kernel<32, 16><<<(16 * 2048 + 127) / 128, 256, 0, stream>>>(
        sA, sB, 16 * 2048);
    // L5: conv 32->64, 3x3 pad1, 8->8
    for (int b0 = 0; b0 < 16; b0 += bg5) {
        conv_z_kernel<32, 8, 3, 8><<<dim3(8 * 4, 4, bg5), 320, 0, stream>>>(
            sB + (size_t)b0 * 32 * 64 * TPAD, Wt3, z64, 64, mode);
        conv_z_mfma_kernel<32, 3, 8><<<dim3(8 * 4, 4, bg5), 320, 0, stream>>>(
            sB + (size_t)b0 * 32 * 64 * TPAD, Wf3, z64, 64, mode);
        int N = bg5 * 4096;
        psp_scan_kernel<<<(N + 63) / 64, 256, 0, stream>>>(
            z64, sA + (size_t)b0 * 4096 * TPAD, N);
    }
    // L6: dense partials + single final scan
    dense_partial_kernel<<<dim3(5, 16, 16), 256, 0, stream>>>(sA, wf32, dpart);
    psp_out_final_kernel<<<160, 320, 0, stream>>>(dpart, d_out, flag);
}

// Round 14
// 1925.198 us; speedup vs baseline: 1.3099x; 1.3099x over previous
//
#include <hip/hip_runtime.h>
#include <hip/hip_bf16.h>
#include <stdint.h>
#include <stddef.h>

#define TPAD 320   // padded time stride (300 real + 20 pad)
#define TREAL 300

// Python-f64 pool weight: float(1.1*10.0)  (validated exact, rounds 7-13)
#define POOL_W   11.000000000000002

typedef double v4d __attribute__((ext_vector_type(4)));

static __device__ __forceinline__ float bf2f(uint16_t b) {
    return __uint_as_float(((uint32_t)b) << 16);
}

// ---------------------------------------------------------------------------
// f64 truncated-alpha IIR + refractory scan (validated exact).
// ---------------------------------------------------------------------------
struct IIRC { double DD, C1, C2, C3, DR; };
static __device__ __forceinline__ IIRC iirc_make() {
    IIRC c;
    c.DD = exp(-0.1);
    c.C1 = exp(1.0) / 10.0;
    c.C2 = exp(-9.0) / 10.0;
    c.C3 = 10.0 * exp(-9.0);
    c.DR = exp(-1.0);
    return c;
}
struct IIRS { double P, Q, P2, Q2, r; };
static __device__ __forceinline__ void iirs_init(IIRS& s) {
    s.P = 0.0; s.Q = 0.0; s.P2 = 0.0; s.Q2 = 0.0; s.r = 0.0;
}
static __device__ __forceinline__ bool iir_step(const IIRC& c, IIRS& st,
                                                double x, double xd) {
    double Qn  = c.DD * (st.Q + st.P);
    double Pn  = fma(c.DD, st.P, x);
    double Q2n = c.DD * (st.Q2 + st.P2);
    double P2n = fma(c.DD, st.P2, xd);
    double a = c.C1 * Qn - c.C2 * Q2n - c.C3 * P2n;
    double u = a + st.r;
    bool s = (u >= 10.0);
    st.r = c.DR * (st.r - (s ? 20.0 : 0.0));
    st.P = Pn; st.Q = Qn; st.P2 = P2n; st.Q2 = Q2n;
    return s;
}

// ---------------------------------------------------------------------------
__global__ void detect_kernel(const uint16_t* __restrict__ w1raw, int* __restrict__ flag)
{
    if (threadIdx.x == 0 && blockIdx.x == 0) {
        int sane = 1;
        for (int i = 0; i < 800; ++i) {
            int e = (w1raw[i] >> 7) & 0xFF;
            if (e >= 131) { sane = 0; break; }
        }
        *flag = sane;   // 1 = bf16, 0 = f32
    }
}

// ---------------------------------------------------------------------------
// MFMA f64 LAYOUT-DISCOVERY probe (r12, VALIDATED on HW: matched and full
// run passed absmax 0.0 -> exact-sum theory + discovered layout correct).
// ---------------------------------------------------------------------------
static __device__ __forceinline__ double probe_w(int a, int b, int s) {
    uint32_t h = (uint32_t)(a * 73856093) ^ (uint32_t)(b * 19349663)
               ^ (uint32_t)(s * 83492791) ^ 0x9e3779b9u;
    h ^= h >> 13; h *= 0x85ebca6bu; h ^= h >> 16;
    int m = 128 + (int)(h & 127u);          // 8-bit mantissa
    int e = -12 + (int)((h >> 7) & 7u);     // small exponent spread
    double v = ldexp((double)m, e);
    return ((h >> 15) & 1u) ? -v : v;
}
static __device__ __forceinline__ double probe_x(int i, int k, int s) {
    return (double)(((i * 5 + k * 3 + s) % 7) < 3 ? 1 : 0);
}
static __device__ __forceinline__ void d_decode(int dvar, int lane, int r,
                                                int& i, int& j) {
    int l15 = lane & 15, l4 = lane >> 4;
    if (dvar == 0)      { i = 4 * l4 + r;  j = l15; }
    else if (dvar == 1) { i = l4 + 4 * r;  j = l15; }
    else                { i = l15;         j = 4 * l4 + r; }
}

__global__ void mfma_probe_kernel(int* __restrict__ mode)
{
    const int lane = (int)threadIdx.x & 63;
    const int l15 = lane & 15;
    const int l4  = lane >> 4;
    int found = 0;
    for (int c = 0; c < 6; ++c) {
        int bvar = c / 3, dvar = c % 3;
        bool ok = true;
        for (int s = 0; s < 4; ++s) {
            double av = probe_x(l15, l4, s);                       // A[i][k]
            double bv = (bvar == 0) ? probe_w(l4, l15, s)          // B: 16k+j
                                    : probe_w(lane & 3, lane >> 2, s); // 4j+k
            v4d cc;
            #pragma unroll
            for (int r = 0; r < 4; ++r) {
                int i, j; d_decode(dvar, lane, r, i, j);
                cc[r] = probe_w(32 + i, j, s + 17);
            }
            v4d d = __builtin_amdgcn_mfma_f64_16x16x4f64(av, bv, cc, 0, 0, 0);
            #pragma unroll
            for (int r = 0; r < 4; ++r) {
                int i, j; d_decode(dvar, lane, r, i, j);
                double e = probe_w(32 + i, j, s + 17);
                #pragma unroll
                for (int k = 0; k < 4; ++k)
                    e = fma(probe_x(i, k, s), probe_w(k, j, s), e);  // exact
                ok &= (__double_as_longlong(e) == __double_as_longlong(d[r]));
            }
        }
        unsigned long long bo = __ballot(ok);
        if (bo == ~0ull && found == 0) found = c + 1;
    }
    if (threadIdx.x == 0) *mode = found;
}

// Conv weights -> f64, transposed to [co_group][tap][16 co-in-group] (serial).
__global__ __launch_bounds__(256) void wtrans_kernel(
    const void* __restrict__ w, double* __restrict__ out, int Co, int CKK,
    const int* __restrict__ flag)
{
    int i = blockIdx.x * 256 + threadIdx.x;
    if (i >= Co * CKK) return;
    int co = i / CKK, r = i - co * CKK;
    double v = (*flag) ? (double)bf2f(((const uint16_t*)w)[i])
                       : (double)((const float*)w)[i];
    out[(size_t)(co >> 4) * CKK * 16 + (size_t)r * 16 + (co & 15)] = v;
}

// Conv weights -> f64 MFMA B-fragments [gy][gks][lane]; lane packing per
// probed B-variant. tap = gks*4 + k; taps >= CKK zero-padded (L1 ragged).
__global__ __launch_bounds__(256) void wtrans_frag_kernel(
    const void* __restrict__ w, double* __restrict__ out,
    int CKK, int KS_TOTAL, int total,
    const int* __restrict__ flag, const int* __restrict__ mode)
{
    int i = blockIdx.x * 256 + threadIdx.x;
    if (i >= total) return;
    int md = *mode;
    int bvar = (md > 0) ? (md - 1) / 3 : 0;
    int lane = i & 63;
    int gks  = (i >> 6) % KS_TOTAL;
    int gy   = (i >> 6) / KS_TOTAL;
    int kl, col;
    if (bvar == 0) { kl = lane >> 4; col = lane & 15; }
    else           { kl = lane & 3;  col = lane >> 2; }
    int tap  = gks * 4 + kl;
    int co   = gy * 16 + col;
    double v = 0.0;
    if (tap < CKK) {
        int src = co * CKK + tap;
        v = (*flag) ? (double)bf2f(((const uint16_t*)w)[src])
                    : (double)((const float*)w)[src];
    }
    out[i] = v;
}

// Dense weights -> f32 (bf16->f32 exact)
__global__ __launch_bounds__(256) void wcvt_kernel(
    const void* __restrict__ w, float* __restrict__ out, int n, const int* __restrict__ flag)
{
    int i = blockIdx.x * 256 + threadIdx.x;
    if (i >= n) return;
    out[i] = (*flag) ? bf2f(((const uint16_t*)w)[i]) : ((const float*)w)[i];
}

__global__ __launch_bounds__(320) void convert_kernel(
    const void* __restrict__ s_in, uint8_t* __restrict__ u8, const int* __restrict__ flag)
{
    int row = blockIdx.x;
    int t = threadIdx.x;
    uint8_t v = 0;
    if (t < TREAL) {
        float x = (*flag) ? bf2f(((const uint16_t*)s_in)[(size_t)row * TREAL + t])
                          : ((const float*)s_in)[(size_t)row * TREAL + t];
        v = (x >= 0.5f) ? 1 : 0;
    }
    u8[(size_t)row * TPAD + t] = v;
}

// ---------------------------------------------------------------------------
// Conv -> z (f64) SERIAL: r9 body verbatim (155 us L3/L5), early-exits when
// MFMA mode active. Separate kernel so MFMA path can't inflate regalloc.
// ---------------------------------------------------------------------------
template<int Ci, int CIB, int K, int Hi>
__global__ __launch_bounds__(320, 3) void conv_z_kernel(
    const uint8_t* __restrict__ sprev,
    const double* __restrict__ Wt,
    double* __restrict__ z,
    int Co_total, const int* __restrict__ mode)
{
    if (*mode != 0) return;
    constexpr int P = 1;
    constexpr int Wi = Hi;
    constexpr int Ho = Hi + 2 * P - K + 1;
    constexpr int Wo = Ho;
    constexpr int KK = K * K;
    constexpr int CKK = Ci * KK;
    constexpr int CW = K + 1;
    constexpr int NROW = CIB * K * CW;
    constexpr int NPASS = Ci / CIB;
    constexpr int WTILE = CIB * KK * 16;
    static_assert(Ci % CIB == 0, "pass split");
    static_assert(Wo % 2 == 0, "pair split");
    static_assert(NROW * 320 + WTILE * 8 <= 60 * 1024, "LDS over limit");

    __shared__ uint32_t stage[NROW * 80];
    __shared__ double wtile[WTILE];

    const int t   = threadIdx.x;
    const int h   = (int)blockIdx.x / (Wo / 2);
    const int w   = ((int)blockIdx.x % (Wo / 2)) * 2;
    const int gy  = (int)blockIdx.y;
    const int co0 = gy * 16;
    const int b   = (int)blockIdx.z;

    double acc0[16], acc1[16];
    #pragma unroll
    for (int c = 0; c < 16; ++c) { acc0[c] = 0.0; acc1[c] = 0.0; }

    const size_t in_b = (size_t)b * Ci * Hi * Wi * TPAD;
    const double* wg = Wt + (size_t)gy * CKK * 16;

    for (int p = 0; p < NPASS; ++p) {
        const int ci0 = p * CIB;
        __syncthreads();
        for (int idx = t; idx < NROW * 20; idx += 320) {
            int r  = idx / 20, dw = idx - (idx / 20) * 20;
            int cl = r / (K * CW);
            int rem = r - cl * (K * CW);
            int ky = rem / CW, cx = rem - ky * CW;
            int row = h - P + ky;
            int col = w - P + cx;
            uint4 v = make_uint4(0, 0, 0, 0);
            if ((unsigned)row < (unsigned)Hi && (unsigned)col < (unsigned)Wi)
                v = *(const uint4*)(sprev + in_b +
                      (((size_t)(ci0 + cl) * Hi + row) * Wi + col) * TPAD + dw * 16);
            ((uint4*)stage)[(size_t)r * 20 + dw] = v;
        }
        for (int i = t; i < WTILE; i += 320)
            wtile[i] = wg[(size_t)ci0 * KK * 16 + i];
        __syncthreads();

        const uint8_t* sbytes = (const uint8_t*)stage;
        #pragma unroll 2
        for (int cl = 0; cl < CIB; ++cl) {
            #pragma unroll
            for (int ky = 0; ky < K; ++ky) {
                #pragma unroll
                for (int kx = 0; kx < K; ++kx) {
                    const int rbase = ((cl * K + ky) * CW + kx) * 320;
                    double x0 = (double)sbytes[rbase + t];
                    double x1 = (double)sbytes[rbase + 320 + t];
                    const double* wrow = wtile + (cl * KK + ky * K + kx) * 16;
                    #pragma unroll
                    for (int c = 0; c < 16; ++c) {
                        double wv = wrow[c];
                        acc0[c] = fma(wv, x0, acc0[c]);
                        acc1[c] = fma(wv, x1, acc1[c]);
                    }
                }
            }
        }
    }

    #pragma unroll
    for (int c = 0; c < 16; ++c) {
        size_t row0 = (((size_t)b * Co_total + co0 + c) * Ho + h) * Wo + w;
        z[row0 * TPAD + t]          = acc0[c];
        z[(row0 + 1) * TPAD + t]    = acc1[c];
    }
}

// ---------------------------------------------------------------------------
// Conv -> z (f64) MFMA, LDS-fed with CONFLICT-FREE 336-B row stride (r14).
// r12 (320-B stride) passed absmax 0.0 at 195 us, feed-bound: 1.97M bank
// conflicts (320 B = 80 dw == 16 mod 32 -> the four k-slot lane groups
// pairwise alias). 336 B = 84 dw == 20 mod 32: row deltas 1..7 put the four
// 4-bank groups on disjoint banks. r13 (global feed) was worse (283 us,
// latency-bound) - LDS staging is the right feed, just needed the pad.
// All math, fragments and stores byte-identical to r12 -> absmax 0.0.
// Grid: (Ho*Wo/2, Co_total/16, Bg), block 320 (5 waves x 8 jb).
// ---------------------------------------------------------------------------
template<int Ci, int CIB, int K, int Hi>
__global__ __launch_bounds__(320) void conv_z_mfma_kernel(
    const uint8_t* __restrict__ sprev,
    const double* __restrict__ Wfrag,    // [Co/16][KS_TOTAL][64]
    double* __restrict__ z,
    int Co_total, const int* __restrict__ mode)
{
    const int md = *mode;
    if (md == 0) return;
    const int dvar = (md - 1) % 3;
    constexpr int P = 1;
    constexpr int Wi = Hi;
    constexpr int Ho = Hi + 2 * P - K + 1;
    constexpr int Wo = Ho;
    constexpr int KK = K * K;
    constexpr int CW = K + 1;
    constexpr int NROW = CIB * K * CW;
    constexpr int NPASS = Ci / CIB;
    constexpr int TPP = CIB * KK;
    constexpr int KSP = (TPP + 3) / 4;
    constexpr int KS_TOTAL = NPASS * KSP;
    constexpr int RS = 336;               // padded row stride (bytes)
    static_assert(Ci % CIB == 0, "pass split");
    static_assert(Wo % 2 == 0, "pair split");
    static_assert(NROW * RS + KSP * 64 * 8 <= 60 * 1024, "LDS over limit");

    __shared__ uint32_t stage[NROW * 84];
    __shared__ double wtile[KSP * 64];

    const int t    = threadIdx.x;
    const int wave = t >> 6;
    const int lane = t & 63;
    const int l15  = lane & 15;
    const int l4   = lane >> 4;
    const int h    = (int)blockIdx.x / (Wo / 2);
    const int w    = ((int)blockIdx.x % (Wo / 2)) * 2;
    const int gy   = (int)blockIdx.y;
    const int co0  = gy * 16;
    const int b    = (int)blockIdx.z;

    v4d acc[8];
    #pragma unroll
    for (int jj = 0; jj < 8; ++jj) acc[jj] = (v4d)(0.0);

    const size_t in_b = (size_t)b * Ci * Hi * Wi * TPAD;
    const double* wfg = Wfrag + (size_t)gy * KS_TOTAL * 64;

    for (int p = 0; p < NPASS; ++p) {
        const int ci0 = p * CIB;
        __syncthreads();
        // stage input halo: padded rows (21 uint4/row; dw 0..19 written)
        for (int idx = t; idx < NROW * 20; idx += 320) {
            int r  = idx / 20, dw = idx - (idx / 20) * 20;
            int cl = r / (K * CW);
            int rem = r - cl * (K * CW);
            int ky = rem / CW, cx = rem - ky * CW;
            int row = h - P + ky;
            int col = w - P + cx;
            uint4 v = make_uint4(0, 0, 0, 0);
            if ((unsigned)row < (unsigned)Hi && (unsigned)col < (unsigned)Wi)
                v = *(const uint4*)(sprev + in_b +
                      (((size_t)(ci0 + cl) * Hi + row) * Wi + col) * TPAD + dw * 16);
            ((uint4*)stage)[(size_t)r * 21 + dw] = v;
        }
        for (int i = t; i < KSP * 64; i += 320)
            wtile[i] = wfg[(size_t)p * KSP * 64 + i];
        __syncthreads();

        const uint8_t* sbytes = (const uint8_t*)stage;
        for (int ks = 0; ks < KSP; ++ks) {
            double bv = wtile[ks * 64 + lane];      // B fragment (probed pack)
            int ltap = ks * 4 + l4;                 // A k-slot = l4 (fixed)
            int rowoff = 0;
            if ((TPP % 4 == 0) || (ltap < TPP)) {
                int cl  = ltap / KK;
                int rem = ltap - cl * KK;
                int ky  = rem / K;
                int kx  = rem - ky * K;
                rowoff = ((cl * K + ky) * CW + kx) * RS;
            }
            const uint8_t* ab = sbytes + rowoff + l15;
            #pragma unroll
            for (int jj = 0; jj < 8; ++jj) {
                int jb = wave * 8 + jj;
                int tile = jb >> 1, px = jb & 1;
                double av = (double)ab[px * RS + tile * 16];
                acc[jj] = __builtin_amdgcn_mfma_f64_16x16x4f64(av, bv, acc[jj], 0, 0, 0);
            }
        }
    }

    // store per probed D-variant (wave-uniform branch), LINEAR z (r12-exact)
    if (dvar == 0) {
        #pragma unroll
        for (int jj = 0; jj < 8; ++jj) {
            int jb = wave * 8 + jj;
            int tile = jb >> 1, px = jb & 1;
            size_t row = (((size_t)b * Co_total + co0 + l15) * Ho + h) * Wo + w + px;
            *(v4d*)(z + row * TPAD + tile * 16 + l4 * 4) = acc[jj];
        }
    } else if (dvar == 1) {
        #pragma unroll
        for (int jj = 0; jj < 8; ++jj) {
            int jb = wave * 8 + jj;
            int tile = jb >> 1, px = jb & 1;
            size_t row = (((size_t)b * Co_total + co0 + l15) * Ho + h) * Wo + w + px;
            #pragma unroll
            for (int r = 0; r < 4; ++r)
                z[row * TPAD + tile * 16 + l4 + 4 * r] = acc[jj][r];
        }
    } else {
        #pragma unroll
        for (int jj = 0; jj < 8; ++jj) {
            int jb = wave * 8 + jj;
            int tile = jb >> 1, px = jb & 1;
            #pragma unroll
            for (int r = 0; r < 4; ++r) {
                size_t row = (((size_t)b * Co_total + co0 + 4 * l4 + r) * Ho + h) * Wo + w + px;
                z[row * TPAD + tile * 16 + l15] = acc[jj][r];
            }
        }
    }
}

// ---------------------------------------------------------------------------
// PSP + scan over z: 64 rows/block (r9, validated).
// ---------------------------------------------------------------------------
__global__ __launch_bounds__(256) void psp_scan_kernel(
    const double* __restrict__ z, uint8_t* __restrict__ sout, int N)
{
    __shared__ uint32_t bits[64 * 11];
    const int tid = threadIdx.x;
    const int n0 = blockIdx.x * 64;
    const int n = n0 + tid;
    const bool active = (tid < 64) && (n < N);

    if (active) {
        const double* zr = z + (size_t)n * TPAD;
        const IIRC c = iirc_make();
        IIRS st; iirs_init(st);
        uint32_t bw = 0;
        #pragma unroll 5
        for (int t0 = 0; t0 < 100; t0 += 4) {
            double2 xa = *(const double2*)(zr + t0);
            double2 xb = *(const double2*)(zr + t0 + 2);
            if (iir_step(c, st, xa.x, 0.0)) bw |= 1u << (t0 & 31);
            if (iir_step(c, st, xa.y, 0.0)) bw |= 1u << ((t0 + 1) & 31);
            if (iir_step(c, st, xb.x, 0.0)) bw |= 1u << ((t0 + 2) & 31);
            if (iir_step(c, st, xb.y, 0.0)) bw |= 1u << ((t0 + 3) & 31);
            if ((t0 & 31) == 28) { bits[tid * 11 + (t0 >> 5)] = bw; bw = 0; }
        }
        #pragma unroll 5
        for (int t0 = 100; t0 < TREAL; t0 += 4) {
            double2 xa = *(const double2*)(zr + t0);
            double2 xb = *(const double2*)(zr + t0 + 2);
            double2 da = *(const double2*)(zr + t0 - 100);
            double2 db = *(const double2*)(zr + t0 - 98);
            if (iir_step(c, st, xa.x, da.x)) bw |= 1u << (t0 & 31);
            if (iir_step(c, st, xa.y, da.y)) bw |= 1u << ((t0 + 1) & 31);
            if (iir_step(c, st, xb.x, db.x)) bw |= 1u << ((t0 + 2) & 31);
            if (iir_step(c, st, xb.y, db.y)) bw |= 1u << ((t0 + 3) & 31);
            if ((t0 & 31) == 28) { bits[tid * 11 + (t0 >> 5)] = bw; bw = 0; }
        }
        bits[tid * 11 + 9] = bw;
    }
    __syncthreads();

    for (int task = tid; task < 64 * 80; task += 256) {
        int nl = task / 80, w = task - nl * 80;
        int ng = n0 + nl;
        if (ng >= N) continue;
        int tb = w * 4;
        uint32_t word = bits[nl * 11 + (tb >> 5)];
        uint32_t o = 0;
        #pragma unroll
        for (int j = 0; j < 4; ++j)
            if ((word >> ((tb + j) & 31)) & 1u) o |= 1u << (8 * j);
        *(uint32_t*)(sout + (size_t)ng * TPAD + tb) = o;
    }
}

// ---------------------------------------------------------------------------
// Pool + PSP + scan v2: LDS cnt tile, coalesced in/out (validated).
// ---------------------------------------------------------------------------
template<int C, int Hi>
__global__ __launch_bounds__(256) void pool_psp_v2_kernel(
    const uint8_t* __restrict__ sprev, uint8_t* __restrict__ sout, int N)
{
    constexpr int Wi = Hi, Ho = Hi / 2, Wo = Wi / 2;
    __shared__ uint32_t cnt[128 * 81];
    __shared__ uint32_t bits[128 * 11];
    const int tid = threadIdx.x;
    const int n0 = blockIdx.x * 128;

    for (int task = tid; task < 128 * 80; task += 256) {
        int nl = task / 80, w = task - nl * 80;
        int n = n0 + nl;
        if (n >= N) continue;
        int wo = n % Wo;  int r1 = n / Wo;
        int ho = r1 % Ho; int r2 = r1 / Ho;
        int cc = r2 % C;  int b  = r2 / C;
        const uint8_t* p0 = sprev +
            ((((size_t)b * C + cc) * Hi + 2 * ho) * Wi + 2 * wo) * TPAD + w * 4;
        uint32_t a0 = *(const uint32_t*)p0;
        uint32_t a1 = *(const uint32_t*)(p0 + TPAD);
        uint32_t a2 = *(const uint32_t*)(p0 + (size_t)Wi * TPAD);
        uint32_t a3 = *(const uint32_t*)(p0 + (size_t)(Wi + 1) * TPAD);
        cnt[nl * 81 + w] = a0 + a1 + a2 + a3;
    }
    __syncthreads();

    if (tid < 128 && n0 + tid < N) {
        const uint8_t* cb = (const uint8_t*)cnt + (size_t)tid * 324;
        const IIRC c = iirc_make();
        IIRS st; iirs_init(st);
        uint32_t bw = 0;
        for (int t = 0; t < 100; ++t) {
            double x = POOL_W * (double)cb[t];
            if (iir_step(c, st, x, 0.0)) bw |= 1u << (t & 31);
            if ((t & 31) == 31) { bits[tid * 11 + (t >> 5)] = bw; bw = 0; }
        }
        for (int t = 100; t < TREAL; ++t) {
            double x  = POOL_W * (double)cb[t];
            double xd = POOL_W * (double)cb[t - 100];
            if (iir_step(c, st, x, xd)) bw |= 1u << (t & 31);
            if ((t & 31) == 31) { bits[tid * 11 + (t >> 5)] = bw; bw = 0; }
        }
        bits[tid * 11 + 9] = bw;
    }
    __syncthreads();

    for (int task = tid; task < 128 * 80; task += 256) {
        int nl = task / 80, w = task - nl * 80;
        int n = n0 + nl;
        if (n >= N) continue;
        int tb = w * 4;
        uint32_t word = bits[nl * 11 + (tb >> 5)];
        uint32_t o = 0;
        #pragma unroll
        for (int j = 0; j < 4; ++j)
            if ((word >> ((tb + j) & 31)) & 1u) o |= 1u << (8 * j);
        *(uint32_t*)(sout + (size_t)n * TPAD + tb) = o;
    }
}

// ---------------------------------------------------------------------------
// Dense partials: grid (5, B, 16) (validated).
// ---------------------------------------------------------------------------
__global__ __launch_bounds__(256) void dense_partial_kernel(
    const uint8_t* __restrict__ s5, const float* __restrict__ Wf,
    double* __restrict__ partial)
{
    const int tc = blockIdx.x, b = blockIdx.y, p = blockIdx.z;
    const int tid = threadIdx.x;
    const int tl = tid & 63, slot = tid >> 6;
    const int t = tc * 64 + tl;
    const int i0 = p * 256 + slot * 64;
    double acc[10];
    #pragma unroll
    for (int o = 0; o < 10; ++o) acc[o] = 0.0;
    const uint8_t* sp = s5 + ((size_t)b * 4096 + i0) * TPAD + t;
    for (int i = 0; i < 64; ++i) {
        float f = (float)sp[(size_t)i * TPAD];
        if (__any(f != 0.f)) {
            #pragma unroll
            for (int o = 0; o < 10; ++o)
                acc[o] = fma((double)Wf[o * 4096 + i0 + i], (double)f, acc[o]);
        }
    }
    __shared__ double red[4][64][10];
    #pragma unroll
    for (int o = 0; o < 10; ++o) red[slot][tl][o] = acc[o];
    __syncthreads();
    if (slot == 0) {
        #pragma unroll
        for (int o = 0; o < 10; ++o) {
            double v = ((red[0][tl][o] + red[1][tl][o]) + red[2][tl][o]) + red[3][tl][o];
            partial[((size_t)p * 160 + (size_t)b * 10 + o) * TPAD + t] = v;
        }
    }
}

// ---------------------------------------------------------------------------
// Final: one launch, block per (b,o) row (validated).
// ---------------------------------------------------------------------------
__global__ __launch_bounds__(320) void psp_out_final_kernel(
    const double* __restrict__ partial, void* __restrict__ out,
    const int* __restrict__ flag)
{
    __shared__ double xs[TPAD];
    __shared__ uint8_t sb[TREAL];
    const int n = blockIdx.x;
    const int t = threadIdx.x;
    double v = 0.0;
    #pragma unroll
    for (int p = 0; p < 16; ++p)
        v += partial[((size_t)p * 160 + n) * TPAD + t];
    xs[t] = v;
    __syncthreads();
    if (t == 0) {
        const IIRC c = iirc_make();
        IIRS st; iirs_init(st);
        for (int i = 0; i < TREAL; ++i) {
            double xd = (i >= 100) ? xs[i - 100] : 0.0;
            sb[i] = iir_step(c, st, xs[i], xd) ? 1 : 0;
        }
    }
    __syncthreads();
    if (t < TREAL) {
        size_t e = (size_t)n * TREAL + t;
        if (*flag) ((uint16_t*)out)[e] = sb[t] ? 0x3F80 : 0;
        else       ((float*)out)[e]    = sb[t] ? 1.0f : 0.0f;
    }
}

// ---------------------------------------------------------------------------
__global__ __launch_bounds__(256) void fill_kernel(float* __restrict__ out, int n, float v)
{
    int i = blockIdx.x * 256 + threadIdx.x;
    if (i < n) out[i] = v;
}

// ---------------------------------------------------------------------------
static inline size_t alignup(size_t x) { return (x + 255) & ~(size_t)255; }
static inline int pick_bg(size_t per_b, size_t budget) {
    const int cand[5] = {16, 8, 4, 2, 1};
    for (int k = 0; k < 5; ++k)
        if (per_b * (size_t)cand[k] <= budget) return cand[k];
    return 0;
}

extern "C" void kernel_launch(void* const* d_in, const int* in_sizes, int n_in,
                              void* d_out, int out_size, void* d_ws, size_t ws_size,
                              hipStream_t stream)
{
    if (n_in != 5 || in_sizes[0] != 16 * 2 * 34 * 34 * 300 || in_sizes[1] != 800 ||
        in_sizes[2] != 4608 || in_sizes[3] != 18432 || in_sizes[4] != 40960 ||
        out_size != 16 * 10 * 300) {
        fill_kernel<<<(out_size + 255) / 256, 256, 0, stream>>>((float*)d_out, out_size, 2.0e5f);
        return;
    }

    const size_t flag_sz  = alignup(sizeof(int));
    const size_t mode_sz  = alignup(sizeof(int));
    const size_t w64_sz   = alignup((size_t)(800 + 4608 + 18432) * 8);
    const size_t wfrag_sz = alignup((size_t)(832 + 4608 + 18432) * 8);
    const size_t wf32_sz  = alignup((size_t)40960 * 4);
    const size_t sin8_sz  = alignup((size_t)16 * 2 * 34 * 34 * TPAD);
    const size_t dpart_sz = alignup((size_t)16 * 160 * TPAD * 8);
    const size_t sA_sz    = alignup((size_t)16 * 16384 * TPAD);
    const size_t sB_sz    = alignup((size_t)16 * 4096 * TPAD);
    const size_t base_sz  = flag_sz + mode_sz + w64_sz + wfrag_sz + wf32_sz +
                            sin8_sz + dpart_sz + sA_sz + sB_sz;
    if (base_sz + 256 > ws_size) {
        fill_kernel<<<(out_size + 255) / 256, 256, 0, stream>>>((float*)d_out, out_size, 1.0e5f);
        return;
    }
    const size_t zbud = ws_size - base_sz - 256;

    const size_t zb1 = (size_t)16 * 1024 * TPAD * 8;
    const size_t zb3 = (size_t)32 * 256 * TPAD * 8;
    const size_t zb5 = (size_t)64 * 64 * TPAD * 8;
    const int bg1 = pick_bg(zb1, zbud), bg3 = pick_bg(zb3, zbud), bg5 = pick_bg(zb5, zbud);
    if (bg1 == 0 || bg3 == 0 || bg5 == 0) {
        fill_kernel<<<(out_size + 255) / 256, 256, 0, stream>>>((float*)d_out, out_size, 1.0e5f);
        return;
    }

    char* base = (char*)d_ws;
    int* flag = (int*)base;          base += flag_sz;
    int* mode = (int*)base;          base += mode_sz;
    double* w64 = (double*)base;     base += w64_sz;
    double* wfrag = (double*)base;   base += wfrag_sz;
    float* wf32 = (float*)base;      base += wf32_sz;
    uint8_t* sin8 = (uint8_t*)base;  base += sin8_sz;
    double* dpart = (double*)base;   base += dpart_sz;
    uint8_t* sA = (uint8_t*)base;    base += sA_sz;
    uint8_t* sB = (uint8_t*)base;    base += sB_sz;
    double* z64 = (double*)base;

    detect_kernel<<<1, 64, 0, stream>>>((const uint16_t*)d_in[1], flag);
    mfma_probe_kernel<<<1, 64, 0, stream>>>(mode);

    double* Wt1 = w64;                 // [1][50][16]
    double* Wt2 = w64 + 800;           // [2][144][16]
    double* Wt3 = w64 + 800 + 4608;    // [4][288][16]
    wtrans_kernel<<<(800 + 255) / 256, 256, 0, stream>>>(d_in[1], Wt1, 16, 50, flag);
    wtrans_kernel<<<(4608 + 255) / 256, 256, 0, stream>>>(d_in[2], Wt2, 32, 144, flag);
    wtrans_kernel<<<(18432 + 255) / 256, 256, 0, stream>>>(d_in[3], Wt3, 64, 288, flag);

    double* Wf1 = wfrag;                  // [1][13][64]
    double* Wf2 = wfrag + 832;            // [2][36][64]
    double* Wf3 = wfrag + 832 + 4608;     // [4][72][64]
    wtrans_frag_kernel<<<(832 + 255) / 256, 256, 0, stream>>>(
        d_in[1], Wf1, 50, 13, 832, flag, mode);
    wtrans_frag_kernel<<<(4608 + 255) / 256, 256, 0, stream>>>(
        d_in[2], Wf2, 144, 36, 4608, flag, mode);
    wtrans_frag_kernel<<<(18432 + 255) / 256, 256, 0, stream>>>(
        d_in[3], Wf3, 288, 72, 18432, flag, mode);

    wcvt_kernel<<<(40960 + 255) / 256, 256, 0, stream>>>(d_in[4], wf32, 40960, flag);
    convert_kernel<<<16 * 2 * 34 * 34, 320, 0, stream>>>(d_in[0], sin8, flag);

    // L1: conv 2->16, 5x5 pad1, 34->32
    for (int b0 = 0; b0 < 16; b0 += bg1) {
        conv_z_kernel<2, 2, 5, 34><<<dim3(32 * 16, 1, bg1), 320, 0, stream>>>(
            sin8 + (size_t)b0 * 2 * 34 * 34 * TPAD, Wt1, z64, 16, mode);
        conv_z_mfma_kernel<2, 2, 5, 34><<<dim3(32 * 16, 1, bg1), 320, 0, stream>>>(
            sin8 + (size_t)b0 * 2 * 34 * 34 * TPAD, Wf1, z64, 16, mode);
        int N = bg1 * 16384;
        psp_scan_kernel<<<(N + 63) / 64, 256, 0, stream>>>(
            z64, sA + (size_t)b0 * 16384 * TPAD, N);
    }
    // L2: pool 32->16
    pool_psp_v2_kernel<16, 32><<<(16 * 4096 + 127) / 128, 256, 0, stream>>>(
        sA, sB, 16 * 4096);
    // L3: conv 16->32, 3x3 pad1, 16->16
    for (int b0 = 0; b0 < 16; b0 += bg3) {
        conv_z_kernel<16, 8, 3, 16><<<dim3(16 * 8, 2, bg3), 320, 0, stream>>>(
            sB + (size_t)b0 * 16 * 256 * TPAD, Wt2, z64, 32, mode);
        conv_z_mfma_kernel<16, 8, 3, 16><<<dim3(16 * 8, 2, bg3), 320, 0, stream>>>(
            sB + (size_t)b0 * 16 * 256 * TPAD, Wf2, z64, 32, mode);
        int N = bg3 * 8192;
        psp_scan_kernel<<<(N + 63) / 64, 256, 0, stream>>>(
            z64, sA + (size_t)b0 * 8192 * TPAD, N);
    }
    // L4: pool 16->8
    pool_psp_v2_kernel<32, 16><<<(16 * 2048 + 127) / 128, 256, 0, stream>>>(
        sA, sB, 16 * 2048);
    // L5: conv 32->64, 3x3 pad1, 8->8
    for (int b0 = 0; b0 < 16; b0 += bg5) {
        conv_z_kernel<32, 8, 3, 8><<<dim3(8 * 4, 4, bg5), 320, 0, stream>>>(
            sB + (size_t)b0 * 32 * 64 * TPAD, Wt3, z64, 64, mode);
        conv_z_mfma_kernel<32, 8, 3, 8><<<dim3(8 * 4, 4, bg5), 320, 0, stream>>>(
            sB + (size_t)b0 * 32 * 64 * TPAD, Wf3, z64, 64, mode);
        int N = bg5 * 4096;
        psp_scan_kernel<<<(N + 63) / 64, 256, 0, stream>>>(
            z64, sA + (size_t)b0 * 4096 * TPAD, N);
    }
    // L6: dense partials + single final scan
    dense_partial_kernel<<<dim3(5, 16, 16), 256, 0, stream>>>(sA, wf32, dpart);
    psp_out_final_kernel<<<160, 320, 0, stream>>>(dpart, d_out, flag);
}

// Round 15
// 1621.787 us; speedup vs baseline: 1.5550x; 1.1871x over previous
//
#include <hip/hip_runtime.h>
#include <hip/hip_bf16.h>
#include <stdint.h>
#include <stddef.h>

#define TPAD 320   // padded time stride (300 real + 20 pad)
#define TREAL 300

// Python-f64 pool weight: float(1.1*10.0)  (validated exact)
#define POOL_W   11.000000000000002

static __device__ __forceinline__ float bf2f(uint16_t b) {
    return __uint_as_float(((uint32_t)b) << 16);
}

// ---------------------------------------------------------------------------
// f64 truncated-alpha IIR + refractory scan (validated exact).
// ---------------------------------------------------------------------------
struct IIRC { double DD, C1, C2, C3, DR; };
static __device__ __forceinline__ IIRC iirc_make() {
    IIRC c;
    c.DD = exp(-0.1);
    c.C1 = exp(1.0) / 10.0;
    c.C2 = exp(-9.0) / 10.0;
    c.C3 = 10.0 * exp(-9.0);
    c.DR = exp(-1.0);
    return c;
}
struct IIRS { double P, Q, P2, Q2, r; };
static __device__ __forceinline__ void iirs_init(IIRS& s) {
    s.P = 0.0; s.Q = 0.0; s.P2 = 0.0; s.Q2 = 0.0; s.r = 0.0;
}
static __device__ __forceinline__ bool iir_step(const IIRC& c, IIRS& st,
                                                double x, double xd) {
    double Qn  = c.DD * (st.Q + st.P);
    double Pn  = fma(c.DD, st.P, x);
    double Q2n = c.DD * (st.Q2 + st.P2);
    double P2n = fma(c.DD, st.P2, xd);
    double a = c.C1 * Qn - c.C2 * Q2n - c.C3 * P2n;
    double u = a + st.r;
    bool s = (u >= 10.0);
    st.r = c.DR * (st.r - (s ? 20.0 : 0.0));
    st.P = Pn; st.Q = Qn; st.P2 = P2n; st.Q2 = Q2n;
    return s;
}

// ---------------------------------------------------------------------------
__global__ void detect_kernel(const uint16_t* __restrict__ w1raw, int* __restrict__ flag)
{
    if (threadIdx.x == 0 && blockIdx.x == 0) {
        int sane = 1;
        for (int i = 0; i < 800; ++i) {
            int e = (w1raw[i] >> 7) & 0xFF;
            if (e >= 131) { sane = 0; break; }
        }
        *flag = sane;   // 1 = bf16, 0 = f32
    }
}

// Conv weights -> f64, transposed to [co_group][tap][16 co-in-group].
__global__ __launch_bounds__(256) void wtrans_kernel(
    const void* __restrict__ w, double* __restrict__ out, int Co, int CKK,
    const int* __restrict__ flag)
{
    int i = blockIdx.x * 256 + threadIdx.x;
    if (i >= Co * CKK) return;
    int co = i / CKK, r = i - co * CKK;
    double v = (*flag) ? (double)bf2f(((const uint16_t*)w)[i])
                       : (double)((const float*)w)[i];
    out[(size_t)(co >> 4) * CKK * 16 + (size_t)r * 16 + (co & 15)] = v;
}

// Dense weights -> f32 (bf16->f32 exact)
__global__ __launch_bounds__(256) void wcvt_kernel(
    const void* __restrict__ w, float* __restrict__ out, int n, const int* __restrict__ flag)
{
    int i = blockIdx.x * 256 + threadIdx.x;
    if (i >= n) return;
    out[i] = (*flag) ? bf2f(((const uint16_t*)w)[i]) : ((const float*)w)[i];
}

__global__ __launch_bounds__(320) void convert_kernel(
    const void* __restrict__ s_in, uint8_t* __restrict__ u8, const int* __restrict__ flag)
{
    int row = blockIdx.x;
    int t = threadIdx.x;
    uint8_t v = 0;
    if (t < TREAL) {
        float x = (*flag) ? bf2f(((const uint16_t*)s_in)[(size_t)row * TREAL + t])
                          : ((const float*)s_in)[(size_t)row * TREAL + t];
        v = (x >= 0.5f) ? 1 : 0;
    }
    u8[(size_t)row * TPAD + t] = v;
}

// ---------------------------------------------------------------------------
// Conv -> z (f64): TERMINAL serial kernel (r9 verbatim; measured best
// 155 us L3/L5). 14-round ledger: beats LDS-MFMA (195), global-MFMA (283),
// sparsity-guard (274), 8-co split (180). f64 MFMA is bitwise-safe here
// (r12: exact sums, layout probed, absmax 0.0) but the 16x16x4 f64 pipe
// delivers only ~40 TF effective with dependent chains at 2 waves/SIMD —
// slower than this VALU path. Occupancy allocator-pinned at 192 VGPR.
// Grid: (Ho*Wo/2, Co_total/16, Bg)
// ---------------------------------------------------------------------------
template<int Ci, int CIB, int K, int Hi>
__global__ __launch_bounds__(320, 3) void conv_z_kernel(
    const uint8_t* __restrict__ sprev,   // chunk-local [Bg][Ci][Hi][Wi][TPAD]
    const double* __restrict__ Wt,       // [Co/16][CKK][16] f64 (exact bf16)
    double* __restrict__ z,              // chunk-local [Bg][Co][Ho][Wo][TPAD]
    int Co_total)
{
    constexpr int P = 1;
    constexpr int Wi = Hi;
    constexpr int Ho = Hi + 2 * P - K + 1;
    constexpr int Wo = Ho;
    constexpr int KK = K * K;
    constexpr int CKK = Ci * KK;
    constexpr int CW = K + 1;             // staged columns for the pair
    constexpr int NROW = CIB * K * CW;    // staged 320-B rows per pass
    constexpr int NPASS = Ci / CIB;
    constexpr int WTILE = CIB * KK * 16;  // f64 weights per pass
    static_assert(Ci % CIB == 0, "pass split");
    static_assert(Wo % 2 == 0, "pair split");
    static_assert(NROW * 320 + WTILE * 8 <= 60 * 1024, "LDS over limit");

    __shared__ uint32_t stage[NROW * 80];
    __shared__ double wtile[WTILE];

    const int t   = threadIdx.x;             // 0..319
    const int h   = (int)blockIdx.x / (Wo / 2);
    const int w   = ((int)blockIdx.x % (Wo / 2)) * 2;
    const int gy  = (int)blockIdx.y;
    const int co0 = gy * 16;
    const int b   = (int)blockIdx.z;

    double acc0[16], acc1[16];
    #pragma unroll
    for (int c = 0; c < 16; ++c) { acc0[c] = 0.0; acc1[c] = 0.0; }

    const size_t in_b = (size_t)b * Ci * Hi * Wi * TPAD;
    const double* wg = Wt + (size_t)gy * CKK * 16;

    for (int p = 0; p < NPASS; ++p) {
        const int ci0 = p * CIB;
        __syncthreads();
        // stage input halo (uint4: 16 B per load)
        for (int idx = t; idx < NROW * 20; idx += 320) {
            int r  = idx / 20, dw = idx - (idx / 20) * 20;
            int cl = r / (K * CW);
            int rem = r - cl * (K * CW);
            int ky = rem / CW, cx = rem - ky * CW;
            int row = h - P + ky;
            int col = w - P + cx;
            uint4 v = make_uint4(0, 0, 0, 0);
            if ((unsigned)row < (unsigned)Hi && (unsigned)col < (unsigned)Wi)
                v = *(const uint4*)(sprev + in_b +
                      (((size_t)(ci0 + cl) * Hi + row) * Wi + col) * TPAD + dw * 16);
            ((uint4*)stage)[(size_t)r * 20 + dw] = v;
        }
        // stage this pass's weight tile (contiguous slice of wg)
        for (int i = t; i < WTILE; i += 320)
            wtile[i] = wg[(size_t)ci0 * KK * 16 + i];
        __syncthreads();

        const uint8_t* sbytes = (const uint8_t*)stage;
        #pragma unroll 2
        for (int cl = 0; cl < CIB; ++cl) {
            #pragma unroll
            for (int ky = 0; ky < K; ++ky) {
                #pragma unroll
                for (int kx = 0; kx < K; ++kx) {
                    const int rbase = ((cl * K + ky) * CW + kx) * 320;
                    double x0 = (double)sbytes[rbase + t];
                    double x1 = (double)sbytes[rbase + 320 + t];
                    const double* wrow = wtile + (cl * KK + ky * K + kx) * 16;
                    #pragma unroll
                    for (int c = 0; c < 16; ++c) {
                        double wv = wrow[c];   // uniform addr -> LDS broadcast
                        acc0[c] = fma(wv, x0, acc0[c]);
                        acc1[c] = fma(wv, x1, acc1[c]);
                    }
                }
            }
        }
    }

    #pragma unroll
    for (int c = 0; c < 16; ++c) {
        size_t row0 = (((size_t)b * Co_total + co0 + c) * Ho + h) * Wo + w;
        z[row0 * TPAD + t]          = acc0[c];
        z[(row0 + 1) * TPAD + t]    = acc1[c];
    }
}

// ---------------------------------------------------------------------------
// PSP + scan over z: lane = row, bits-in-registers -> LDS transpose ->
// coalesced u32 stores. 64 rows/block (r9, validated).
// ---------------------------------------------------------------------------
__global__ __launch_bounds__(256) void psp_scan_kernel(
    const double* __restrict__ z, uint8_t* __restrict__ sout, int N)
{
    __shared__ uint32_t bits[64 * 11];
    const int tid = threadIdx.x;
    const int n0 = blockIdx.x * 64;
    const int n = n0 + tid;
    const bool active = (tid < 64) && (n < N);

    if (active) {
        const double* zr = z + (size_t)n * TPAD;
        const IIRC c = iirc_make();
        IIRS st; iirs_init(st);
        uint32_t bw = 0;
        #pragma unroll 5
        for (int t0 = 0; t0 < 100; t0 += 4) {
            double2 xa = *(const double2*)(zr + t0);
            double2 xb = *(const double2*)(zr + t0 + 2);
            if (iir_step(c, st, xa.x, 0.0)) bw |= 1u << (t0 & 31);
            if (iir_step(c, st, xa.y, 0.0)) bw |= 1u << ((t0 + 1) & 31);
            if (iir_step(c, st, xb.x, 0.0)) bw |= 1u << ((t0 + 2) & 31);
            if (iir_step(c, st, xb.y, 0.0)) bw |= 1u << ((t0 + 3) & 31);
            if ((t0 & 31) == 28) { bits[tid * 11 + (t0 >> 5)] = bw; bw = 0; }
        }
        #pragma unroll 5
        for (int t0 = 100; t0 < TREAL; t0 += 4) {
            double2 xa = *(const double2*)(zr + t0);
            double2 xb = *(const double2*)(zr + t0 + 2);
            double2 da = *(const double2*)(zr + t0 - 100);
            double2 db = *(const double2*)(zr + t0 - 98);
            if (iir_step(c, st, xa.x, da.x)) bw |= 1u << (t0 & 31);
            if (iir_step(c, st, xa.y, da.y)) bw |= 1u << ((t0 + 1) & 31);
            if (iir_step(c, st, xb.x, db.x)) bw |= 1u << ((t0 + 2) & 31);
            if (iir_step(c, st, xb.y, db.y)) bw |= 1u << ((t0 + 3) & 31);
            if ((t0 & 31) == 28) { bits[tid * 11 + (t0 >> 5)] = bw; bw = 0; }
        }
        bits[tid * 11 + 9] = bw;
    }
    __syncthreads();

    for (int task = tid; task < 64 * 80; task += 256) {
        int nl = task / 80, w = task - nl * 80;
        int ng = n0 + nl;
        if (ng >= N) continue;
        int tb = w * 4;
        uint32_t word = bits[nl * 11 + (tb >> 5)];
        uint32_t o = 0;
        #pragma unroll
        for (int j = 0; j < 4; ++j)
            if ((word >> ((tb + j) & 31)) & 1u) o |= 1u << (8 * j);
        *(uint32_t*)(sout + (size_t)ng * TPAD + tb) = o;
    }
}

// ---------------------------------------------------------------------------
// Pool + PSP + scan v2: LDS cnt tile, coalesced in/out (validated).
// ---------------------------------------------------------------------------
template<int C, int Hi>
__global__ __launch_bounds__(256) void pool_psp_v2_kernel(
    const uint8_t* __restrict__ sprev, uint8_t* __restrict__ sout, int N)
{
    constexpr int Wi = Hi, Ho = Hi / 2, Wo = Wi / 2;
    __shared__ uint32_t cnt[128 * 81];
    __shared__ uint32_t bits[128 * 11];
    const int tid = threadIdx.x;
    const int n0 = blockIdx.x * 128;

    for (int task = tid; task < 128 * 80; task += 256) {
        int nl = task / 80, w = task - nl * 80;
        int n = n0 + nl;
        if (n >= N) continue;
        int wo = n % Wo;  int r1 = n / Wo;
        int ho = r1 % Ho; int r2 = r1 / Ho;
        int cc = r2 % C;  int b  = r2 / C;
        const uint8_t* p0 = sprev +
            ((((size_t)b * C + cc) * Hi + 2 * ho) * Wi + 2 * wo) * TPAD + w * 4;
        uint32_t a0 = *(const uint32_t*)p0;
        uint32_t a1 = *(const uint32_t*)(p0 + TPAD);
        uint32_t a2 = *(const uint32_t*)(p0 + (size_t)Wi * TPAD);
        uint32_t a3 = *(const uint32_t*)(p0 + (size_t)(Wi + 1) * TPAD);
        cnt[nl * 81 + w] = a0 + a1 + a2 + a3;
    }
    __syncthreads();

    if (tid < 128 && n0 + tid < N) {
        const uint8_t* cb = (const uint8_t*)cnt + (size_t)tid * 324;
        const IIRC c = iirc_make();
        IIRS st; iirs_init(st);
        uint32_t bw = 0;
        for (int t = 0; t < 100; ++t) {
            double x = POOL_W * (double)cb[t];
            if (iir_step(c, st, x, 0.0)) bw |= 1u << (t & 31);
            if ((t & 31) == 31) { bits[tid * 11 + (t >> 5)] = bw; bw = 0; }
        }
        for (int t = 100; t < TREAL; ++t) {
            double x  = POOL_W * (double)cb[t];
            double xd = POOL_W * (double)cb[t - 100];
            if (iir_step(c, st, x, xd)) bw |= 1u << (t & 31);
            if ((t & 31) == 31) { bits[tid * 11 + (t >> 5)] = bw; bw = 0; }
        }
        bits[tid * 11 + 9] = bw;
    }
    __syncthreads();

    for (int task = tid; task < 128 * 80; task += 256) {
        int nl = task / 80, w = task - nl * 80;
        int n = n0 + nl;
        if (n >= N) continue;
        int tb = w * 4;
        uint32_t word = bits[nl * 11 + (tb >> 5)];
        uint32_t o = 0;
        #pragma unroll
        for (int j = 0; j < 4; ++j)
            if ((word >> ((tb + j) & 31)) & 1u) o |= 1u << (8 * j);
        *(uint32_t*)(sout + (size_t)n * TPAD + tb) = o;
    }
}

// ---------------------------------------------------------------------------
// Dense partials: grid (5, B, 16) (validated).
// ---------------------------------------------------------------------------
__global__ __launch_bounds__(256) void dense_partial_kernel(
    const uint8_t* __restrict__ s5, const float* __restrict__ Wf,
    double* __restrict__ partial)
{
    const int tc = blockIdx.x, b = blockIdx.y, p = blockIdx.z;
    const int tid = threadIdx.x;
    const int tl = tid & 63, slot = tid >> 6;
    const int t = tc * 64 + tl;
    const int i0 = p * 256 + slot * 64;
    double acc[10];
    #pragma unroll
    for (int o = 0; o < 10; ++o) acc[o] = 0.0;
    const uint8_t* sp = s5 + ((size_t)b * 4096 + i0) * TPAD + t;
    for (int i = 0; i < 64; ++i) {
        float f = (float)sp[(size_t)i * TPAD];
        if (__any(f != 0.f)) {
            #pragma unroll
            for (int o = 0; o < 10; ++o)
                acc[o] = fma((double)Wf[o * 4096 + i0 + i], (double)f, acc[o]);
        }
    }
    __shared__ double red[4][64][10];
    #pragma unroll
    for (int o = 0; o < 10; ++o) red[slot][tl][o] = acc[o];
    __syncthreads();
    if (slot == 0) {
        #pragma unroll
        for (int o = 0; o < 10; ++o) {
            double v = ((red[0][tl][o] + red[1][tl][o]) + red[2][tl][o]) + red[3][tl][o];
            partial[((size_t)p * 160 + (size_t)b * 10 + o) * TPAD + t] = v;
        }
    }
}

// ---------------------------------------------------------------------------
// Final: one launch, block per (b,o) row (validated).
// ---------------------------------------------------------------------------
__global__ __launch_bounds__(320) void psp_out_final_kernel(
    const double* __restrict__ partial, void* __restrict__ out,
    const int* __restrict__ flag)
{
    __shared__ double xs[TPAD];
    __shared__ uint8_t sb[TREAL];
    const int n = blockIdx.x;
    const int t = threadIdx.x;
    double v = 0.0;
    #pragma unroll
    for (int p = 0; p < 16; ++p)
        v += partial[((size_t)p * 160 + n) * TPAD + t];
    xs[t] = v;
    __syncthreads();
    if (t == 0) {
        const IIRC c = iirc_make();
        IIRS st; iirs_init(st);
        for (int i = 0; i < TREAL; ++i) {
            double xd = (i >= 100) ? xs[i - 100] : 0.0;
            sb[i] = iir_step(c, st, xs[i], xd) ? 1 : 0;
        }
    }
    __syncthreads();
    if (t < TREAL) {
        size_t e = (size_t)n * TREAL + t;
        if (*flag) ((uint16_t*)out)[e] = sb[t] ? 0x3F80 : 0;
        else       ((float*)out)[e]    = sb[t] ? 1.0f : 0.0f;
    }
}

// ---------------------------------------------------------------------------
__global__ __launch_bounds__(256) void fill_kernel(float* __restrict__ out, int n, float v)
{
    int i = blockIdx.x * 256 + threadIdx.x;
    if (i < n) out[i] = v;
}

// ---------------------------------------------------------------------------
static inline size_t alignup(size_t x) { return (x + 255) & ~(size_t)255; }
static inline int pick_bg(size_t per_b, size_t budget) {
    const int cand[5] = {16, 8, 4, 2, 1};
    for (int k = 0; k < 5; ++k)
        if (per_b * (size_t)cand[k] <= budget) return cand[k];
    return 0;
}

extern "C" void kernel_launch(void* const* d_in, const int* in_sizes, int n_in,
                              void* d_out, int out_size, void* d_ws, size_t ws_size,
                              hipStream_t stream)
{
    if (n_in != 5 || in_sizes[0] != 16 * 2 * 34 * 34 * 300 || in_sizes[1] != 800 ||
        in_sizes[2] != 4608 || in_sizes[3] != 18432 || in_sizes[4] != 40960 ||
        out_size != 16 * 10 * 300) {
        fill_kernel<<<(out_size + 255) / 256, 256, 0, stream>>>((float*)d_out, out_size, 2.0e5f);
        return;
    }

    const size_t flag_sz  = alignup(sizeof(int));
    const size_t w64_sz   = alignup((size_t)(800 + 4608 + 18432) * 8);
    const size_t wf32_sz  = alignup((size_t)40960 * 4);
    const size_t sin8_sz  = alignup((size_t)16 * 2 * 34 * 34 * TPAD);
    const size_t dpart_sz = alignup((size_t)16 * 160 * TPAD * 8);
    const size_t sA_sz    = alignup((size_t)16 * 16384 * TPAD);
    const size_t sB_sz    = alignup((size_t)16 * 4096 * TPAD);
    const size_t base_sz  = flag_sz + w64_sz + wf32_sz + sin8_sz + dpart_sz + sA_sz + sB_sz;
    if (base_sz + 256 > ws_size) {
        fill_kernel<<<(out_size + 255) / 256, 256, 0, stream>>>((float*)d_out, out_size, 1.0e5f);
        return;
    }
    const size_t zbud = ws_size - base_sz - 256;

    const size_t zb1 = (size_t)16 * 1024 * TPAD * 8;
    const size_t zb3 = (size_t)32 * 256 * TPAD * 8;
    const size_t zb5 = (size_t)64 * 64 * TPAD * 8;
    const int bg1 = pick_bg(zb1, zbud), bg3 = pick_bg(zb3, zbud), bg5 = pick_bg(zb5, zbud);
    if (bg1 == 0 || bg3 == 0 || bg5 == 0) {
        fill_kernel<<<(out_size + 255) / 256, 256, 0, stream>>>((float*)d_out, out_size, 1.0e5f);
        return;
    }

    char* base = (char*)d_ws;
    int* flag = (int*)base;          base += flag_sz;
    double* w64 = (double*)base;     base += w64_sz;
    float* wf32 = (float*)base;      base += wf32_sz;
    uint8_t* sin8 = (uint8_t*)base;  base += sin8_sz;
    double* dpart = (double*)base;   base += dpart_sz;
    uint8_t* sA = (uint8_t*)base;    base += sA_sz;
    uint8_t* sB = (uint8_t*)base;    base += sB_sz;
    double* z64 = (double*)base;

    detect_kernel<<<1, 64, 0, stream>>>((const uint16_t*)d_in[1], flag);

    double* Wt1 = w64;                 // [1][50][16]
    double* Wt2 = w64 + 800;           // [2][144][16]
    double* Wt3 = w64 + 800 + 4608;    // [4][288][16]
    wtrans_kernel<<<(800 + 255) / 256, 256, 0, stream>>>(d_in[1], Wt1, 16, 50, flag);
    wtrans_kernel<<<(4608 + 255) / 256, 256, 0, stream>>>(d_in[2], Wt2, 32, 144, flag);
    wtrans_kernel<<<(18432 + 255) / 256, 256, 0, stream>>>(d_in[3], Wt3, 64, 288, flag);
    wcvt_kernel<<<(40960 + 255) / 256, 256, 0, stream>>>(d_in[4], wf32, 40960, flag);
    convert_kernel<<<16 * 2 * 34 * 34, 320, 0, stream>>>(d_in[0], sin8, flag);

    // L1: conv 2->16, 5x5 pad1, 34->32 (pair; stage 19.2 KB + wtile 6.4 KB)
    for (int b0 = 0; b0 < 16; b0 += bg1) {
        conv_z_kernel<2, 2, 5, 34><<<dim3(32 * 16, 1, bg1), 320, 0, stream>>>(
            sin8 + (size_t)b0 * 2 * 34 * 34 * TPAD, Wt1, z64, 16);
        int N = bg1 * 16384;
        psp_scan_kernel<<<(N + 63) / 64, 256, 0, stream>>>(
            z64, sA + (size_t)b0 * 16384 * TPAD, N);
    }
    // L2: pool 32->16, coalesced v2
    pool_psp_v2_kernel<16, 32><<<(16 * 4096 + 127) / 128, 256, 0, stream>>>(
        sA, sB, 16 * 4096);
    // L3: conv 16->32, 3x3 pad1, 16->16 (pair; CIB=8, 2 passes, 30.7+9.2 KB)
    for (int b0 = 0; b0 < 16; b0 += bg3) {
        conv_z_kernel<16, 8, 3, 16><<<dim3(16 * 8, 2, bg3), 320, 0, stream>>>(
            sB + (size_t)b0 * 16 * 256 * TPAD, Wt2, z64, 32);
        int N = bg3 * 8192;
        psp_scan_kernel<<<(N + 63) / 64, 256, 0, stream>>>(
            z64, sA + (size_t)b0 * 8192 * TPAD, N);
    }
    // L4: pool 16->8, coalesced v2
    pool_psp_v2_kernel<32, 16><<<(16 * 2048 + 127) / 128, 256, 0, stream>>>(
        sA, sB, 16 * 2048);
    // L5: conv 32->64, 3x3 pad1, 8->8 (pair; CIB=8, 4 passes, 30.7+9.2 KB)
    for (int b0 = 0; b0 < 16; b0 += bg5) {
        conv_z_kernel<32, 8, 3, 8><<<dim3(8 * 4, 4, bg5), 320, 0, stream>>>(
            sB + (size_t)b0 * 32 * 64 * TPAD, Wt3, z64, 64);
        int N = bg5 * 4096;
        psp_scan_kernel<<<(N + 63) / 64, 256, 0, stream>>>(
            z64, sA + (size_t)b0 * 4096 * TPAD, N);
    }
    // L6: dense partials + single final scan
    dense_partial_kernel<<<dim3(5, 16, 16), 256, 0, stream>>>(sA, wf32, dpart);
    psp_out_final_kernel<<<160, 320, 0, stream>>>(dpart, d_out, flag);
}